// Round 14
// baseline (193.551 us; speedup 1.0000x reference)
//
#include <hip/hip_runtime.h>
#include <hip/hip_fp16.h>
#include <math.h>

#define NT 262144
#define KD 512
#define NE 64
#define DE 64

constexpr int BM = 128;       // tokens per block
constexpr int NS = KD / 32;   // 16 K-steps
constexpr int WS_EN = 32768;  // u32 offset of e_norm f16-split planes
constexpr int LD2 = 68;       // h_norm [tok][d] stride (floats)
constexpr float RSC  = 4096.0f;          // residual-plane scale (2^12)
constexpr float IRSC = 1.0f / 4096.0f;

using f32x4 = __attribute__((ext_vector_type(4))) float;
using f16x8 = __attribute__((ext_vector_type(8))) _Float16;

typedef const __attribute__((address_space(1))) unsigned int* gp1_t;
typedef __attribute__((address_space(3))) unsigned int* lp3_t;

// ---- 2-term f16 split: x = a1 + a2s*2^-12 + eps, |eps| <= 2^-22|x| + 1.5e-8.
__device__ __forceinline__ void splitf16(float4 lo, float4 hi,
                                         f16x8& o1, f16x8& o2) {
    float x[8] = {lo.x, lo.y, lo.z, lo.w, hi.x, hi.y, hi.z, hi.w};
    union { unsigned int u[4]; f16x8 v; } r1, r2;
    #pragma unroll
    for (int p = 0; p < 4; ++p) {
        float f0 = x[2 * p], f1 = x[2 * p + 1];
        __half2 h1 = __float22half2_rn(make_float2(f0, f1));
        float2 bk = __half22float2(h1);
        __half2 h2 = __float22half2_rn(make_float2((f0 - bk.x) * RSC,
                                                   (f1 - bk.y) * RSC));
        r1.u[p] = *reinterpret_cast<unsigned int*>(&h1);
        r2.u[p] = *reinterpret_cast<unsigned int*>(&h2);
    }
    o1 = r1.v; o2 = r2.v;
}

__device__ __forceinline__ f16x8 ld_frag(const unsigned int* p) {
    union { uint4 q; f16x8 v; } u;
    u.q = *(const uint4*)p;
    return u.v;
}

// ---- prep (unchanged from round 13) ----
__global__ void prep(const float* __restrict__ W, const float* __restrict__ E,
                     unsigned int* __restrict__ ws) {
    const int tid = threadIdx.x;
    if (blockIdx.x < 16) {
        const int idx = blockIdx.x * 256 + tid;     // chunk: row*64 + k8
        const int row = idx >> 6, k8 = idx & 63;
        const float* src = W + (size_t)row * KD + k8 * 8;
        float4 lo = *(const float4*)src, hi = *(const float4*)(src + 4);
        f16x8 o1, o2;
        splitf16(lo, hi, o1, o2);
        union { f16x8 v; uint4 q; } u1, u2;
        u1.v = o1; u2.v = o2;
        const int ks = k8 >> 2, lk = k8 & 3, ct = row >> 4, lr = row & 15;
        const int g = ks * 4 + ct, lane = lk * 16 + lr;
        unsigned int* base = ws + (size_t)g * 512 + lane * 4;
        *(uint4*)(base)       = u1.q;
        *(uint4*)(base + 256) = u2.q;
    } else {
        const int er = tid >> 2, part = tid & 3;    // expert row, d-quarter
        float ss = 0.f;
        float4 ev[4];
        #pragma unroll
        for (int u = 0; u < 4; ++u) {
            ev[u] = *(const float4*)(E + er * DE + part * 16 + u * 4);
            ss = fmaf(ev[u].x, ev[u].x, ss);
            ss = fmaf(ev[u].y, ev[u].y, ss);
            ss = fmaf(ev[u].z, ev[u].z, ss);
            ss = fmaf(ev[u].w, ev[u].w, ss);
        }
        ss += __shfl_xor(ss, 1, 64);
        ss += __shfl_xor(ss, 2, 64);
        const float inv_e = 1.0f / fmaxf(sqrtf(ss), 1e-12f);
        #pragma unroll
        for (int u = 0; u < 4; ++u) {
            ev[u].x *= inv_e; ev[u].y *= inv_e; ev[u].z *= inv_e; ev[u].w *= inv_e;
        }
        #pragma unroll
        for (int half = 0; half < 2; ++half) {      // 8 consecutive d each
            const int d0 = part * 16 + half * 8;
            f16x8 o1, o2;
            splitf16(ev[half * 2], ev[half * 2 + 1], o1, o2);
            union { f16x8 v; uint4 q; } u1, u2;
            u1.v = o1; u2.v = o2;
            const int k2 = d0 >> 5, kg = (d0 >> 3) & 3;
            const int ge = k2 * 4 + (er >> 4), l = (er & 15) | (kg << 4);
            unsigned int* base = ws + WS_EN + (size_t)ge * 512 + l * 4;
            *(uint4*)(base)       = u1.q;
            *(uint4*)(base + 256) = u2.q;
        }
    }
}

// ---- fused main (round-13 tail; A-operand DIRECT TO REGISTERS) ----
// K-loop was LDS-BW-bound (~102 B/cyc vs ~85-128 ceiling; r11's -25% LDS
// bytes paid exactly linearly). A's LDS round-trip (DMA-write + same-wave
// read-back, 32KB/block-step) was pure latency-hiding overhead: replaced by
// 4 global_load_dwordx4/step into a double-buffered register set with one
// step of prefetch cover (~2K cyc >> 900 HBM). LDS traffic -44%. Identical
// values reach splitf16 -> bit-identical output. B path unchanged (12KB...
// 8KB/step via DMA-LDS once per block, double-buffered, 1 barrier/step).
// LDS: [0,4096) B dbuf 16KB; h_norm overlay [0,8704) after the K-loop.
__global__ __launch_bounds__(256, 4) void moe_all(const float* __restrict__ h,
                                                  const unsigned int* __restrict__ wsW,
                                                  const float* __restrict__ tau_p,
                                                  float* __restrict__ out) {
    __shared__ float smem[8704];

    const int tid = threadIdx.x;
    const int lane = tid & 63;
    const int wv = tid >> 6;          // wave 0..3 -> tokens [wv*32, wv*32+32)
    const int lr = lane & 15;         // fragment row/col within 16
    const int lk = lane >> 4;         // k-group 0..3
    const long tok0 = (long)blockIdx.x * BM;
    const long wtok = tok0 + wv * 32;

    f32x4 acc[2][4], ac2[2][4];       // main + scaled-residual accumulators
    #pragma unroll
    for (int rt = 0; rt < 2; ++rt)
        #pragma unroll
        for (int ct = 0; ct < 4; ++ct) {
            acc[rt][ct] = (f32x4){0.f, 0.f, 0.f, 0.f};
            ac2[rt][ct] = (f32x4){0.f, 0.f, 0.f, 0.f};
        }

#define STAGE_B(CUR, KS)                                                       \
    {                                                                          \
        _Pragma("unroll")                                                      \
        for (int i = 0; i < 2; ++i) {                                          \
            const unsigned int* g = wsW + (size_t)(KS) * 2048 + i * 1024       \
                                    + wv * 256 + lane * 4;                     \
            float* l = smem + (CUR) * 2048 + i * 1024 + wv * 256;              \
            __builtin_amdgcn_global_load_lds((gp1_t)(const void*)g,            \
                                             (lp3_t)(void*)l, 16, 0, 0);       \
        }                                                                      \
    }

// One K-step: consume A regs (CL*/CH*), prefetch A(KS+1) into NL*/NH* and
// B(KS+1) into the other LDS buffer; split; 8 ds_read + 24 MFMA.
#define PHASE(CL0, CH0, CL1, CH1, NL0, NH0, NL1, NH1, KS, LAST)                \
    {                                                                          \
        asm volatile("s_waitcnt vmcnt(0)" ::: "memory");  /* A(KS)+B(KS) in */ \
        __builtin_amdgcn_s_barrier();          /* B(KS) visible block-wide */  \
        if (!(LAST)) {                                                         \
            STAGE_B(((KS) + 1) & 1, (KS) + 1);                                 \
            const int o = ((KS) + 1) * 32;                                     \
            NL0 = *(const float4*)(pa0 + o); NH0 = *(const float4*)(pa0 + o + 4); \
            NL1 = *(const float4*)(pa1 + o); NH1 = *(const float4*)(pa1 + o + 4); \
        }                                                                      \
        __builtin_amdgcn_sched_barrier(0);                                     \
        f16x8 a1[2], a2[2];                                                    \
        splitf16(CL0, CH0, a1[0], a2[0]);                                      \
        splitf16(CL1, CH1, a1[1], a2[1]);                                      \
        _Pragma("unroll")                                                      \
        for (int ct = 0; ct < 4; ++ct) {                                       \
            const unsigned int* bb =                                           \
                (const unsigned int*)(smem + ((KS) & 1) * 2048)                \
                + ct * 512 + lane * 4;                                         \
            f16x8 b1 = ld_frag(bb);                                            \
            f16x8 b2 = ld_frag(bb + 256);                                      \
            f32x4 c0 = acc[0][ct], c1 = acc[1][ct];                            \
            f32x4 d0 = ac2[0][ct], d1 = ac2[1][ct];                            \
            c0 = __builtin_amdgcn_mfma_f32_16x16x32_f16(a1[0], b1, c0, 0, 0, 0); \
            c1 = __builtin_amdgcn_mfma_f32_16x16x32_f16(a1[1], b1, c1, 0, 0, 0); \
            d0 = __builtin_amdgcn_mfma_f32_16x16x32_f16(a1[0], b2, d0, 0, 0, 0); \
            d1 = __builtin_amdgcn_mfma_f32_16x16x32_f16(a1[1], b2, d1, 0, 0, 0); \
            d0 = __builtin_amdgcn_mfma_f32_16x16x32_f16(a2[0], b1, d0, 0, 0, 0); \
            d1 = __builtin_amdgcn_mfma_f32_16x16x32_f16(a2[1], b1, d1, 0, 0, 0); \
            acc[0][ct] = c0; acc[1][ct] = c1;                                  \
            ac2[0][ct] = d0; ac2[1][ct] = d1;                                  \
        }                                                                      \
    }

    // A base pointers: lane reads h[wtok + {0,16} + lr][ks*32 + lk*8 .. +8)
    const float* pa0 = h + (wtok + 0 * 16 + lr) * (long)KD + lk * 8;
    const float* pa1 = h + (wtok + 1 * 16 + lr) * (long)KD + lk * 8;

    // prologue: B(0) DMA + A(0) register loads
    STAGE_B(0, 0);
    float4 xl0 = *(const float4*)(pa0), xh0 = *(const float4*)(pa0 + 4);
    float4 xl1 = *(const float4*)(pa1), xh1 = *(const float4*)(pa1 + 4);
    float4 yl0 = xl0, yh0 = xh0, yl1 = xl1, yh1 = xh1;  // written before read

    for (int ks = 0; ks < NS; ks += 2) {
        PHASE(xl0, xh0, xl1, xh1, yl0, yh0, yl1, yh1, ks,     0);
        PHASE(yl0, yh0, yl1, yh1, xl0, xh0, xl1, xh1, ks + 1, (ks + 1 == NS - 1));
    }

    // fold the scaled-residual accumulator back: proj = acc + ac2 * 2^-12
    #pragma unroll
    for (int rt = 0; rt < 2; ++rt)
        #pragma unroll
        for (int ct = 0; ct < 4; ++ct)
            #pragma unroll
            for (int r = 0; r < 4; ++r)
                acc[rt][ct][r] = fmaf(ac2[rt][ct][r], IRSC, acc[rt][ct][r]);

    // ---- per-token L2 norm from fragments ----
    float inv_n[2][4];
    #pragma unroll
    for (int rt = 0; rt < 2; ++rt) {
        #pragma unroll
        for (int r = 0; r < 4; ++r) {
            float ss = 0.f;
            #pragma unroll
            for (int ct = 0; ct < 4; ++ct)
                ss = fmaf(acc[rt][ct][r], acc[rt][ct][r], ss);
            ss += __shfl_xor(ss, 1, 64);
            ss += __shfl_xor(ss, 2, 64);
            ss += __shfl_xor(ss, 4, 64);
            ss += __shfl_xor(ss, 8, 64);
            inv_n[rt][r] = 1.0f / fmaxf(sqrtf(ss), 1e-12f);
        }
    }

    __syncthreads();   // all waves done reading B LDS (h_norm overlays it)

    // h_norm -> smem as [tok][d], stride 68; each wave touches only its tokens
    #pragma unroll
    for (int rt = 0; rt < 2; ++rt)
        #pragma unroll
        for (int ct = 0; ct < 4; ++ct)
            #pragma unroll
            for (int r = 0; r < 4; ++r) {
                const int t = wv * 32 + rt * 16 + lk * 4 + r;
                smem[t * LD2 + ct * 16 + lr] = acc[rt][ct][r] * inv_n[rt][r];
            }

    // ---- stage 2 (MFMA, f16 2-plane): scores[32][64] per wave ----
    const unsigned int* wsE = wsW + WS_EN;
    f32x4 sc[2][4], sc2[2][4];
    #pragma unroll
    for (int rt = 0; rt < 2; ++rt)
        #pragma unroll
        for (int ce = 0; ce < 4; ++ce) {
            sc[rt][ce]  = (f32x4){0.f, 0.f, 0.f, 0.f};
            sc2[rt][ce] = (f32x4){0.f, 0.f, 0.f, 0.f};
        }

    #pragma unroll
    for (int k2 = 0; k2 < 2; ++k2) {
        f16x8 ha1[2], ha2[2];
        #pragma unroll
        for (int rt = 0; rt < 2; ++rt) {
            const float* ra = smem + (wv * 32 + rt * 16 + lr) * LD2 + k2 * 32 + lk * 8;
            float4 lo = *(const float4*)ra;
            float4 hi = *(const float4*)(ra + 4);
            splitf16(lo, hi, ha1[rt], ha2[rt]);
        }
        #pragma unroll
        for (int ce = 0; ce < 4; ++ce) {
            const unsigned int* bb = wsE + (k2 * 4 + ce) * 512 + lane * 4;
            f16x8 b1 = ld_frag(bb);
            f16x8 b2 = ld_frag(bb + 256);
            #pragma unroll
            for (int rt = 0; rt < 2; ++rt) {
                f32x4 c = sc[rt][ce], d = sc2[rt][ce];
                c = __builtin_amdgcn_mfma_f32_16x16x32_f16(ha1[rt], b1, c, 0, 0, 0);
                d = __builtin_amdgcn_mfma_f32_16x16x32_f16(ha1[rt], b2, d, 0, 0, 0);
                d = __builtin_amdgcn_mfma_f32_16x16x32_f16(ha2[rt], b1, d, 0, 0, 0);
                sc[rt][ce] = c; sc2[rt][ce] = d;
            }
        }
    }

    // ---- epilogue on C-fragment layout; top-2 first, m = v1 ----
    const float inv_tau = 1.0f / tau_p[0];
    float* outS = out;                        // sparse_gates [NT][64]
    float* outI = out + (size_t)NT * 64;      // topk_indices [NT][2] (as float)
    float* outF = out + (size_t)NT * 66;      // full_gates   [NT][64]

    #pragma unroll
    for (int rt = 0; rt < 2; ++rt) {
        #pragma unroll
        for (int r = 0; r < 4; ++r) {
            const long tok = tok0 + wv * 32 + rt * 16 + lk * 4 + r;
            float s[4];
            #pragma unroll
            for (int ce = 0; ce < 4; ++ce)
                s[ce] = fmaf(sc2[rt][ce][r], IRSC, sc[rt][ce][r]) * inv_tau;

            // top-2 via order-preserving u64 keys: (ord(v) << 6) | (63 - e).
            unsigned long long k1 = 0ULL, k2 = 0ULL;   // 0 < any real key
            #pragma unroll
            for (int ce = 0; ce < 4; ++ce) {
                unsigned int ou = __float_as_uint(s[ce]);
                ou = (ou & 0x80000000u) ? ~ou : (ou | 0x80000000u);
                unsigned long long key = ((unsigned long long)ou << 6)
                                       | (unsigned long long)(63 - (ce * 16 + lr));
                if (key > k1) { k2 = k1; k1 = key; }
                else if (key > k2) { k2 = key; }
            }
            #pragma unroll
            for (int msk = 1; msk <= 8; msk <<= 1) {
                unsigned long long o1 = __shfl_xor(k1, msk, 64);
                unsigned long long o2 = __shfl_xor(k2, msk, 64);
                unsigned long long hi = k1 > o1 ? k1 : o1;
                unsigned long long lo = k1 > o1 ? o1 : k1;
                unsigned long long m2 = k2 > o2 ? k2 : o2;
                k2 = lo > m2 ? lo : m2;
                k1 = hi;
            }
            const int i1 = 63 - (int)(k1 & 63ULL);
            const int i2 = 63 - (int)(k2 & 63ULL);
            const unsigned int u1 = (unsigned int)(k1 >> 6);
            const unsigned int u2 = (unsigned int)(k2 >> 6);
            const float v1 = __uint_as_float((u1 & 0x80000000u) ? (u1 ^ 0x80000000u) : ~u1);
            const float v2 = __uint_as_float((u2 & 0x80000000u) ? (u2 ^ 0x80000000u) : ~u2);

            // softmax max == v1 (top-1 score): no separate max-reduction
            const float m = v1;

            float g[4], z = 0.f;
            #pragma unroll
            for (int ce = 0; ce < 4; ++ce) { g[ce] = __expf(s[ce] - m); z += g[ce]; }
            z += __shfl_xor(z, 1, 64);
            z += __shfl_xor(z, 2, 64);
            z += __shfl_xor(z, 4, 64);
            z += __shfl_xor(z, 8, 64);
            const float invZ = 1.0f / z;

            #pragma unroll
            for (int ce = 0; ce < 4; ++ce)
                outF[tok * 64 + ce * 16 + lr] = g[ce] * invZ;

            // softmax over the two top GATE values; gv1 = exp(0)*invZ = invZ
            const float gv1 = invZ;
            const float gv2 = __expf(v2 - m) * invZ;
            const float qq = __expf(gv2 - gv1);
            const float w1 = 1.0f / (1.0f + qq);
            const float w2 = qq * w1;

            #pragma unroll
            for (int ce = 0; ce < 4; ++ce) {
                int e = ce * 16 + lr;
                outS[tok * 64 + e] = (e == i1) ? w1 : ((e == i2) ? w2 : 0.0f);
            }
            if (lr == 0) {
                *(float2*)(outI + tok * 2) = make_float2((float)i1, (float)i2);
            }
        }
    }
#undef STAGE_B
#undef PHASE
}

extern "C" void kernel_launch(void* const* d_in, const int* in_sizes, int n_in,
                              void* d_out, int out_size, void* d_ws, size_t ws_size,
                              hipStream_t stream) {
    const float* h   = (const float*)d_in[0];
    const float* W   = (const float*)d_in[1];
    const float* E   = (const float*)d_in[2];
    const float* tau = (const float*)d_in[3];
    float* out = (float*)d_out;
    unsigned int* ws = (unsigned int*)d_ws;   // 128KB W frags + 16KB e_norm frags

    prep<<<17, 256, 0, stream>>>(W, E, ws);
    moe_all<<<NT / BM, 256, 0, stream>>>(h, ws, tau, out);
}

// Round 15
// 162.094 us; speedup vs baseline: 1.1941x; 1.1941x over previous
//
#include <hip/hip_runtime.h>
#include <hip/hip_fp16.h>
#include <math.h>

#define NT 262144
#define KD 512
#define NE 64
#define DE 64

constexpr int BM = 256;       // tokens per block (8 waves x 32)
constexpr int NS = KD / 32;   // 16 K-steps
constexpr int WS_EN = 32768;  // u32 offset of e_norm f16-split planes
constexpr int LT = 36;        // stage-2 per-wave transpose stride (16B-aligned rows)
constexpr float RSC  = 4096.0f;          // residual-plane scale (2^12)
constexpr float IRSC = 1.0f / 4096.0f;

using f32x4 = __attribute__((ext_vector_type(4))) float;
using f16x8 = __attribute__((ext_vector_type(8))) _Float16;

typedef const __attribute__((address_space(1))) unsigned int* gp1_t;
typedef __attribute__((address_space(3))) unsigned int* lp3_t;

// ---- 2-term f16 split: x = a1 + a2s*2^-12 + eps, |eps| <= 2^-22|x| + 1.5e-8.
__device__ __forceinline__ void splitf16(float4 lo, float4 hi,
                                         f16x8& o1, f16x8& o2) {
    float x[8] = {lo.x, lo.y, lo.z, lo.w, hi.x, hi.y, hi.z, hi.w};
    union { unsigned int u[4]; f16x8 v; } r1, r2;
    #pragma unroll
    for (int p = 0; p < 4; ++p) {
        float f0 = x[2 * p], f1 = x[2 * p + 1];
        __half2 h1 = __float22half2_rn(make_float2(f0, f1));
        float2 bk = __half22float2(h1);
        __half2 h2 = __float22half2_rn(make_float2((f0 - bk.x) * RSC,
                                                   (f1 - bk.y) * RSC));
        r1.u[p] = *reinterpret_cast<unsigned int*>(&h1);
        r2.u[p] = *reinterpret_cast<unsigned int*>(&h2);
    }
    o1 = r1.v; o2 = r2.v;
}

__device__ __forceinline__ f16x8 ld_frag(const unsigned int* p) {
    union { uint4 q; f16x8 v; } u;
    u.q = *(const uint4*)p;
    return u.v;
}

// ---- prep (unchanged from round 13) ----
__global__ void prep(const float* __restrict__ W, const float* __restrict__ E,
                     unsigned int* __restrict__ ws) {
    const int tid = threadIdx.x;
    if (blockIdx.x < 16) {
        const int idx = blockIdx.x * 256 + tid;     // chunk: row*64 + k8
        const int row = idx >> 6, k8 = idx & 63;
        const float* src = W + (size_t)row * KD + k8 * 8;
        float4 lo = *(const float4*)src, hi = *(const float4*)(src + 4);
        f16x8 o1, o2;
        splitf16(lo, hi, o1, o2);
        union { f16x8 v; uint4 q; } u1, u2;
        u1.v = o1; u2.v = o2;
        const int ks = k8 >> 2, lk = k8 & 3, ct = row >> 4, lr = row & 15;
        const int g = ks * 4 + ct, lane = lk * 16 + lr;
        unsigned int* base = ws + (size_t)g * 512 + lane * 4;
        *(uint4*)(base)       = u1.q;
        *(uint4*)(base + 256) = u2.q;
    } else {
        const int er = tid >> 2, part = tid & 3;    // expert row, d-quarter
        float ss = 0.f;
        float4 ev[4];
        #pragma unroll
        for (int u = 0; u < 4; ++u) {
            ev[u] = *(const float4*)(E + er * DE + part * 16 + u * 4);
            ss = fmaf(ev[u].x, ev[u].x, ss);
            ss = fmaf(ev[u].y, ev[u].y, ss);
            ss = fmaf(ev[u].z, ev[u].z, ss);
            ss = fmaf(ev[u].w, ev[u].w, ss);
        }
        ss += __shfl_xor(ss, 1, 64);
        ss += __shfl_xor(ss, 2, 64);
        const float inv_e = 1.0f / fmaxf(sqrtf(ss), 1e-12f);
        #pragma unroll
        for (int u = 0; u < 4; ++u) {
            ev[u].x *= inv_e; ev[u].y *= inv_e; ev[u].z *= inv_e; ev[u].w *= inv_e;
        }
        #pragma unroll
        for (int half = 0; half < 2; ++half) {      // 8 consecutive d each
            const int d0 = part * 16 + half * 8;
            f16x8 o1, o2;
            splitf16(ev[half * 2], ev[half * 2 + 1], o1, o2);
            union { f16x8 v; uint4 q; } u1, u2;
            u1.v = o1; u2.v = o2;
            const int k2 = d0 >> 5, kg = (d0 >> 3) & 3;
            const int ge = k2 * 4 + (er >> 4), l = (er & 15) | (kg << 4);
            unsigned int* base = ws + WS_EN + (size_t)ge * 512 + l * 4;
            *(uint4*)(base)       = u1.q;
            *(uint4*)(base + 256) = u2.q;
        }
    }
}

// ---- fused main (r13 per-wave structure; BM=256, 8 waves) ----
// r14 proved the K-loop binder is the TA/L1 request path (A-in-reg's
// scattered loads +42us); r13's DMA paths are TA-minimal per instruction.
// Remaining TA lever: B was re-DMA'd identically by every 128-token block.
// BM=256 halves per-token B DMA traffic (TA-B events and L2 reads /2) and
// halves barriers per token. Per-wave work, A path, and all K-loop numerics
// are byte-identical to r13 -> bit-identical output.
// LDS 48KB: [0,4096) B dbuf | [4096,12288) A slices (8 x 1KB). Stage-2 uses
// the r10-verified per-wave chunked transpose (LT=36 for 16B-aligned rows).
__global__ __launch_bounds__(512, 4) void moe_all(const float* __restrict__ h,
                                                  const unsigned int* __restrict__ wsW,
                                                  const float* __restrict__ tau_p,
                                                  float* __restrict__ out) {
    __shared__ float smem[12288];

    const int tid = threadIdx.x;
    const int lane = tid & 63;
    const int wv = tid >> 6;          // wave 0..7 -> tokens [wv*32, wv*32+32)
    const int lr = lane & 15;         // fragment row/col within 16
    const int lk = lane >> 4;         // k-group 0..3
    const long tok0 = (long)blockIdx.x * BM;

    f32x4 acc[2][4], ac2[2][4];       // main + scaled-residual accumulators
    #pragma unroll
    for (int rt = 0; rt < 2; ++rt)
        #pragma unroll
        for (int ct = 0; ct < 4; ++ct) {
            acc[rt][ct] = (f32x4){0.f, 0.f, 0.f, 0.f};
            ac2[rt][ct] = (f32x4){0.f, 0.f, 0.f, 0.f};
        }

    // A: wave wv stages its own 32-token slice (4KB), XOR-pre-swizzled source
#define STAGE_A(KS)                                                            \
    {                                                                          \
        _Pragma("unroll")                                                      \
        for (int n = 0; n < 4; ++n) {                                          \
            const int flat = (wv * 4 + n) * 64 + lane;                         \
            const int t = flat >> 3, q = flat & 7;                             \
            const int qs = q ^ (t & 7);                                        \
            const float* g = h + (tok0 + t) * (long)KD + (KS) * 32 + qs * 4;   \
            float* l = smem + 4096 + wv * 1024 + n * 256;                      \
            __builtin_amdgcn_global_load_lds((gp1_t)(const void*)g,            \
                                             (lp3_t)(void*)l, 16, 0, 0);       \
        }                                                                      \
    }

    // B: whole block (512 thr) copies step KS's 8KB in ONE inst per thread
#define STAGE_B(CUR, KS)                                                       \
    {                                                                          \
        const unsigned int* g = wsW + (size_t)(KS) * 2048 + wv * 256 + lane * 4; \
        float* l = smem + (CUR) * 2048 + wv * 256;                             \
        __builtin_amdgcn_global_load_lds((gp1_t)(const void*)g,                \
                                         (lp3_t)(void*)l, 16, 0, 0);           \
    }

    STAGE_B(0, 0);
    STAGE_A(0);

    const int sw = lr & 7;
    const int q0 = (lk * 2) ^ sw;
    const int q1 = (lk * 2 + 1) ^ sw;
    const float* abase = smem + 4096 + wv * 1024;

    for (int ks = 0; ks < NS; ++ks) {
        const int cur = ks & 1;
        asm volatile("s_waitcnt vmcnt(0)" ::: "memory");
        __builtin_amdgcn_s_barrier();
        if (ks + 1 < NS) { STAGE_B(cur ^ 1, ks + 1); }
        __builtin_amdgcn_sched_barrier(0);

        float4 xl0 = *(const float4*)(abase + lr * 32 + q0 * 4);
        float4 xh0 = *(const float4*)(abase + lr * 32 + q1 * 4);
        float4 xl1 = *(const float4*)(abase + (lr + 16) * 32 + q0 * 4);
        float4 xh1 = *(const float4*)(abase + (lr + 16) * 32 + q1 * 4);
        asm volatile("s_waitcnt lgkmcnt(0)" ::: "memory");  // A regs ready
        if (ks + 1 < NS) { STAGE_A(ks + 1); }               // reuse A buffer
        __builtin_amdgcn_sched_barrier(0);

        f16x8 a1[2], a2[2];
        splitf16(xl0, xh0, a1[0], a2[0]);
        splitf16(xl1, xh1, a1[1], a2[1]);

        #pragma unroll
        for (int ct = 0; ct < 4; ++ct) {
            const unsigned int* bb =
                (const unsigned int*)(smem + cur * 2048) + ct * 512 + lane * 4;
            f16x8 b1 = ld_frag(bb);
            f16x8 b2 = ld_frag(bb + 256);
            f32x4 c0 = acc[0][ct], c1 = acc[1][ct];
            f32x4 d0 = ac2[0][ct], d1 = ac2[1][ct];
            c0 = __builtin_amdgcn_mfma_f32_16x16x32_f16(a1[0], b1, c0, 0, 0, 0);
            c1 = __builtin_amdgcn_mfma_f32_16x16x32_f16(a1[1], b1, c1, 0, 0, 0);
            d0 = __builtin_amdgcn_mfma_f32_16x16x32_f16(a1[0], b2, d0, 0, 0, 0);
            d1 = __builtin_amdgcn_mfma_f32_16x16x32_f16(a1[1], b2, d1, 0, 0, 0);
            d0 = __builtin_amdgcn_mfma_f32_16x16x32_f16(a2[0], b1, d0, 0, 0, 0);
            d1 = __builtin_amdgcn_mfma_f32_16x16x32_f16(a2[1], b1, d1, 0, 0, 0);
            acc[0][ct] = c0; acc[1][ct] = c1;
            ac2[0][ct] = d0; ac2[1][ct] = d1;
        }
    }

    // fold the scaled-residual accumulator back: proj = acc + ac2 * 2^-12
    #pragma unroll
    for (int rt = 0; rt < 2; ++rt)
        #pragma unroll
        for (int ct = 0; ct < 4; ++ct)
            #pragma unroll
            for (int r = 0; r < 4; ++r)
                acc[rt][ct][r] = fmaf(ac2[rt][ct][r], IRSC, acc[rt][ct][r]);

    // ---- per-token L2 norm from fragments ----
    float inv_n[2][4];
    #pragma unroll
    for (int rt = 0; rt < 2; ++rt) {
        #pragma unroll
        for (int r = 0; r < 4; ++r) {
            float ss = 0.f;
            #pragma unroll
            for (int ct = 0; ct < 4; ++ct)
                ss = fmaf(acc[rt][ct][r], acc[rt][ct][r], ss);
            ss += __shfl_xor(ss, 1, 64);
            ss += __shfl_xor(ss, 2, 64);
            ss += __shfl_xor(ss, 4, 64);
            ss += __shfl_xor(ss, 8, 64);
            inv_n[rt][r] = 1.0f / fmaxf(sqrtf(ss), 1e-12f);
        }
    }

    __syncthreads();   // all staging LDS traffic done; scratch reuse safe

    // ---- stage 2 (MFMA, chunked per-wave transpose): scores[32][64]/wave ----
    // Per-wave PRIVATE scratch: 32 tok x 36 floats at smem + wv*1152 (36.9KB).
    // Two d-halves: write half (ct pair) -> read A-frags -> MFMA; repeat.
    const unsigned int* wsE = wsW + WS_EN;
    float* wreg = smem + wv * 1152;
    f32x4 sc[2][4], sc2[2][4];
    #pragma unroll
    for (int rt = 0; rt < 2; ++rt)
        #pragma unroll
        for (int ce = 0; ce < 4; ++ce) {
            sc[rt][ce]  = (f32x4){0.f, 0.f, 0.f, 0.f};
            sc2[rt][ce] = (f32x4){0.f, 0.f, 0.f, 0.f};
        }

    #pragma unroll
    for (int k2 = 0; k2 < 2; ++k2) {
        // write d-half: d_local = cl*16 + lr (ct = k2*2+cl), rows rt*16+lk*4+r
        #pragma unroll
        for (int rt = 0; rt < 2; ++rt)
            #pragma unroll
            for (int cl = 0; cl < 2; ++cl)
                #pragma unroll
                for (int r = 0; r < 4; ++r) {
                    const int ct = k2 * 2 + cl;
                    wreg[(rt * 16 + lk * 4 + r) * LT + cl * 16 + lr] =
                        acc[rt][ct][r] * inv_n[rt][r];
                }
        // read A-frags (within-wave LDS write->read; compiler orders lgkmcnt)
        f16x8 ha1[2], ha2[2];
        #pragma unroll
        for (int rt = 0; rt < 2; ++rt) {
            const float* ra = wreg + (rt * 16 + lr) * LT + lk * 8;
            float4 lo = *(const float4*)ra;
            float4 hi = *(const float4*)(ra + 4);
            splitf16(lo, hi, ha1[rt], ha2[rt]);
        }
        #pragma unroll
        for (int ce = 0; ce < 4; ++ce) {
            const unsigned int* bb = wsE + (k2 * 4 + ce) * 512 + lane * 4;
            f16x8 b1 = ld_frag(bb);
            f16x8 b2 = ld_frag(bb + 256);
            #pragma unroll
            for (int rt = 0; rt < 2; ++rt) {
                f32x4 c = sc[rt][ce], d = sc2[rt][ce];
                c = __builtin_amdgcn_mfma_f32_16x16x32_f16(ha1[rt], b1, c, 0, 0, 0);
                d = __builtin_amdgcn_mfma_f32_16x16x32_f16(ha1[rt], b2, d, 0, 0, 0);
                d = __builtin_amdgcn_mfma_f32_16x16x32_f16(ha2[rt], b1, d, 0, 0, 0);
                sc[rt][ce] = c; sc2[rt][ce] = d;
            }
        }
    }

    // ---- epilogue on C-fragment layout; top-2 first, m = v1 ----
    const float inv_tau = 1.0f / tau_p[0];
    float* outS = out;                        // sparse_gates [NT][64]
    float* outI = out + (size_t)NT * 64;      // topk_indices [NT][2] (as float)
    float* outF = out + (size_t)NT * 66;      // full_gates   [NT][64]

    #pragma unroll
    for (int rt = 0; rt < 2; ++rt) {
        #pragma unroll
        for (int r = 0; r < 4; ++r) {
            const long tok = tok0 + wv * 32 + rt * 16 + lk * 4 + r;
            float s[4];
            #pragma unroll
            for (int ce = 0; ce < 4; ++ce)
                s[ce] = fmaf(sc2[rt][ce][r], IRSC, sc[rt][ce][r]) * inv_tau;

            // top-2 via order-preserving u64 keys: (ord(v) << 6) | (63 - e).
            unsigned long long k1 = 0ULL, k2 = 0ULL;   // 0 < any real key
            #pragma unroll
            for (int ce = 0; ce < 4; ++ce) {
                unsigned int ou = __float_as_uint(s[ce]);
                ou = (ou & 0x80000000u) ? ~ou : (ou | 0x80000000u);
                unsigned long long key = ((unsigned long long)ou << 6)
                                       | (unsigned long long)(63 - (ce * 16 + lr));
                if (key > k1) { k2 = k1; k1 = key; }
                else if (key > k2) { k2 = key; }
            }
            #pragma unroll
            for (int msk = 1; msk <= 8; msk <<= 1) {
                unsigned long long o1 = __shfl_xor(k1, msk, 64);
                unsigned long long o2 = __shfl_xor(k2, msk, 64);
                unsigned long long hi = k1 > o1 ? k1 : o1;
                unsigned long long lo = k1 > o1 ? o1 : k1;
                unsigned long long m2 = k2 > o2 ? k2 : o2;
                k2 = lo > m2 ? lo : m2;
                k1 = hi;
            }
            const int i1 = 63 - (int)(k1 & 63ULL);
            const int i2 = 63 - (int)(k2 & 63ULL);
            const unsigned int u1 = (unsigned int)(k1 >> 6);
            const unsigned int u2 = (unsigned int)(k2 >> 6);
            const float v1 = __uint_as_float((u1 & 0x80000000u) ? (u1 ^ 0x80000000u) : ~u1);
            const float v2 = __uint_as_float((u2 & 0x80000000u) ? (u2 ^ 0x80000000u) : ~u2);

            // softmax max == v1 (top-1 score): no separate max-reduction
            const float m = v1;

            float g[4], z = 0.f;
            #pragma unroll
            for (int ce = 0; ce < 4; ++ce) { g[ce] = __expf(s[ce] - m); z += g[ce]; }
            z += __shfl_xor(z, 1, 64);
            z += __shfl_xor(z, 2, 64);
            z += __shfl_xor(z, 4, 64);
            z += __shfl_xor(z, 8, 64);
            const float invZ = 1.0f / z;

            #pragma unroll
            for (int ce = 0; ce < 4; ++ce)
                outF[tok * 64 + ce * 16 + lr] = g[ce] * invZ;

            // softmax over the two top GATE values; gv1 = exp(0)*invZ = invZ
            const float gv1 = invZ;
            const float gv2 = __expf(v2 - m) * invZ;
            const float qq = __expf(gv2 - gv1);
            const float w1 = 1.0f / (1.0f + qq);
            const float w2 = qq * w1;

            #pragma unroll
            for (int ce = 0; ce < 4; ++ce) {
                int e = ce * 16 + lr;
                outS[tok * 64 + e] = (e == i1) ? w1 : ((e == i2) ? w2 : 0.0f);
            }
            if (lr == 0) {
                *(float2*)(outI + tok * 2) = make_float2((float)i1, (float)i2);
            }
        }
    }
#undef STAGE_A
#undef STAGE_B
}

extern "C" void kernel_launch(void* const* d_in, const int* in_sizes, int n_in,
                              void* d_out, int out_size, void* d_ws, size_t ws_size,
                              hipStream_t stream) {
    const float* h   = (const float*)d_in[0];
    const float* W   = (const float*)d_in[1];
    const float* E   = (const float*)d_in[2];
    const float* tau = (const float*)d_in[3];
    float* out = (float*)d_out;
    unsigned int* ws = (unsigned int*)d_ws;   // 128KB W frags + 16KB e_norm frags

    prep<<<17, 256, 0, stream>>>(W, E, ws);
    moe_all<<<NT / BM, 512, 0, stream>>>(h, ws, tau, out);
}

// Round 16
// 154.655 us; speedup vs baseline: 1.2515x; 1.0481x over previous
//
#include <hip/hip_runtime.h>
#include <hip/hip_fp16.h>
#include <math.h>

#define NT 262144
#define KD 512
#define NE 64
#define DE 64

constexpr int BM = 128;       // tokens per block (4 waves x 32) -- r13 revert
constexpr int NS = KD / 32;   // 16 K-steps
constexpr int WS_EN = 32768;  // u32 offset of e_norm f16-split planes
constexpr int LD2 = 68;       // h_norm [tok][d] stride (floats)
constexpr float RSC  = 4096.0f;          // residual-plane scale (2^12)
constexpr float IRSC = 1.0f / 4096.0f;

using f32x4 = __attribute__((ext_vector_type(4))) float;
using f16x8 = __attribute__((ext_vector_type(8))) _Float16;

typedef const __attribute__((address_space(1))) unsigned int* gp1_t;
typedef __attribute__((address_space(3))) unsigned int* lp3_t;

// ---- 2-term f16 split: x = a1 + a2s*2^-12 + eps, |eps| <= 2^-22|x| + 1.5e-8.
__device__ __forceinline__ void splitf16(float4 lo, float4 hi,
                                         f16x8& o1, f16x8& o2) {
    float x[8] = {lo.x, lo.y, lo.z, lo.w, hi.x, hi.y, hi.z, hi.w};
    union { unsigned int u[4]; f16x8 v; } r1, r2;
    #pragma unroll
    for (int p = 0; p < 4; ++p) {
        float f0 = x[2 * p], f1 = x[2 * p + 1];
        __half2 h1 = __float22half2_rn(make_float2(f0, f1));
        float2 bk = __half22float2(h1);
        __half2 h2 = __float22half2_rn(make_float2((f0 - bk.x) * RSC,
                                                   (f1 - bk.y) * RSC));
        r1.u[p] = *reinterpret_cast<unsigned int*>(&h1);
        r2.u[p] = *reinterpret_cast<unsigned int*>(&h2);
    }
    o1 = r1.v; o2 = r2.v;
}

__device__ __forceinline__ f16x8 ld_frag(const unsigned int* p) {
    union { uint4 q; f16x8 v; } u;
    u.q = *(const uint4*)p;
    return u.v;
}

// ---- prep (unchanged from round 13) ----
__global__ void prep(const float* __restrict__ W, const float* __restrict__ E,
                     unsigned int* __restrict__ ws) {
    const int tid = threadIdx.x;
    if (blockIdx.x < 16) {
        const int idx = blockIdx.x * 256 + tid;     // chunk: row*64 + k8
        const int row = idx >> 6, k8 = idx & 63;
        const float* src = W + (size_t)row * KD + k8 * 8;
        float4 lo = *(const float4*)src, hi = *(const float4*)(src + 4);
        f16x8 o1, o2;
        splitf16(lo, hi, o1, o2);
        union { f16x8 v; uint4 q; } u1, u2;
        u1.v = o1; u2.v = o2;
        const int ks = k8 >> 2, lk = k8 & 3, ct = row >> 4, lr = row & 15;
        const int g = ks * 4 + ct, lane = lk * 16 + lr;
        unsigned int* base = ws + (size_t)g * 512 + lane * 4;
        *(uint4*)(base)       = u1.q;
        *(uint4*)(base + 256) = u2.q;
    } else {
        const int er = tid >> 2, part = tid & 3;    // expert row, d-quarter
        float ss = 0.f;
        float4 ev[4];
        #pragma unroll
        for (int u = 0; u < 4; ++u) {
            ev[u] = *(const float4*)(E + er * DE + part * 16 + u * 4);
            ss = fmaf(ev[u].x, ev[u].x, ss);
            ss = fmaf(ev[u].y, ev[u].y, ss);
            ss = fmaf(ev[u].z, ev[u].z, ss);
            ss = fmaf(ev[u].w, ev[u].w, ss);
        }
        ss += __shfl_xor(ss, 1, 64);
        ss += __shfl_xor(ss, 2, 64);
        const float inv_e = 1.0f / fmaxf(sqrtf(ss), 1e-12f);
        #pragma unroll
        for (int u = 0; u < 4; ++u) {
            ev[u].x *= inv_e; ev[u].y *= inv_e; ev[u].z *= inv_e; ev[u].w *= inv_e;
        }
        #pragma unroll
        for (int half = 0; half < 2; ++half) {      // 8 consecutive d each
            const int d0 = part * 16 + half * 8;
            f16x8 o1, o2;
            splitf16(ev[half * 2], ev[half * 2 + 1], o1, o2);
            union { f16x8 v; uint4 q; } u1, u2;
            u1.v = o1; u2.v = o2;
            const int k2 = d0 >> 5, kg = (d0 >> 3) & 3;
            const int ge = k2 * 4 + (er >> 4), l = (er & 15) | (kg << 4);
            unsigned int* base = ws + WS_EN + (size_t)ge * 512 + l * 4;
            *(uint4*)(base)       = u1.q;
            *(uint4*)(base + 256) = u2.q;
        }
    }
}

// ---- fused main (r13 revert + A-read hoist) ----
// r13 structure (measured best, 151.2us): BM=128/4 waves, A per-wave LDS
// slice via DMA, B 8KB/step DMA'd once per block double-buffered, one
// barrier/step, f16 2-plane split, MFMA stage-2, u64-key top-2 epilogue.
// Tweak vs r13: staging issues A BEFORE B, so vmcnt(2) at step top retires
// exactly the wave's 4 A-DMAs (in-order retirement); the 4 A ds_reads then
// issue ABOVE the vmcnt(0)+s_barrier, overlapping their latency and B's
// landing with the barrier convoy wait. All ordering guarantees unchanged.
__global__ __launch_bounds__(256, 4) void moe_all(const float* __restrict__ h,
                                                  const unsigned int* __restrict__ wsW,
                                                  const float* __restrict__ tau_p,
                                                  float* __restrict__ out) {
    __shared__ float smem[8704];

    const int tid = threadIdx.x;
    const int lane = tid & 63;
    const int wv = tid >> 6;          // wave 0..3 -> tokens [wv*32, wv*32+32)
    const int lr = lane & 15;         // fragment row/col within 16
    const int lk = lane >> 4;         // k-group 0..3
    const long tok0 = (long)blockIdx.x * BM;

    f32x4 acc[2][4], ac2[2][4];       // main + scaled-residual accumulators
    #pragma unroll
    for (int rt = 0; rt < 2; ++rt)
        #pragma unroll
        for (int ct = 0; ct < 4; ++ct) {
            acc[rt][ct] = (f32x4){0.f, 0.f, 0.f, 0.f};
            ac2[rt][ct] = (f32x4){0.f, 0.f, 0.f, 0.f};
        }

#define STAGE_A(KS)                                                            \
    {                                                                          \
        _Pragma("unroll")                                                      \
        for (int n = 0; n < 4; ++n) {                                          \
            const int flat = (wv * 4 + n) * 64 + lane;                         \
            const int t = flat >> 3, q = flat & 7;                             \
            const int qs = q ^ (t & 7);                                        \
            const float* g = h + (tok0 + t) * (long)KD + (KS) * 32 + qs * 4;   \
            float* l = smem + 4096 + wv * 1024 + n * 256;                      \
            __builtin_amdgcn_global_load_lds((gp1_t)(const void*)g,            \
                                             (lp3_t)(void*)l, 16, 0, 0);       \
        }                                                                      \
    }

#define STAGE_B(CUR, KS)                                                       \
    {                                                                          \
        _Pragma("unroll")                                                      \
        for (int i = 0; i < 2; ++i) {                                          \
            const unsigned int* g = wsW + (size_t)(KS) * 2048 + i * 1024       \
                                    + wv * 256 + lane * 4;                     \
            float* l = smem + (CUR) * 2048 + i * 1024 + wv * 256;              \
            __builtin_amdgcn_global_load_lds((gp1_t)(const void*)g,            \
                                             (lp3_t)(void*)l, 16, 0, 0);       \
        }                                                                      \
    }

    // prologue: A first (oldest in vmcnt queue), then B
    STAGE_A(0);
    STAGE_B(0, 0);

    const int sw = lr & 7;
    const int q0 = (lk * 2) ^ sw;
    const int q1 = (lk * 2 + 1) ^ sw;
    const float* abase = smem + 4096 + wv * 1024;

    for (int ks = 0; ks < NS; ++ks) {
        const int cur = ks & 1;
        // A(ks) = 4 oldest outstanding; B(ks):2 may still be in flight
        asm volatile("s_waitcnt vmcnt(2)" ::: "memory");
        float4 xl0 = *(const float4*)(abase + lr * 32 + q0 * 4);
        float4 xh0 = *(const float4*)(abase + lr * 32 + q1 * 4);
        float4 xl1 = *(const float4*)(abase + (lr + 16) * 32 + q0 * 4);
        float4 xh1 = *(const float4*)(abase + (lr + 16) * 32 + q1 * 4);
        asm volatile("s_waitcnt vmcnt(0)" ::: "memory");    // B(ks) landed
        __builtin_amdgcn_s_barrier();                       // visible block-wide
        asm volatile("s_waitcnt lgkmcnt(0)" ::: "memory");  // A regs ready
        if (ks + 1 < NS) {
            STAGE_A(ks + 1);               // reuse A buffer (reads returned)
            STAGE_B(cur ^ 1, ks + 1);      // other B buffer (all reads done)
        }
        __builtin_amdgcn_sched_barrier(0);

        f16x8 a1[2], a2[2];
        splitf16(xl0, xh0, a1[0], a2[0]);
        splitf16(xl1, xh1, a1[1], a2[1]);

        #pragma unroll
        for (int ct = 0; ct < 4; ++ct) {
            const unsigned int* bb =
                (const unsigned int*)(smem + cur * 2048) + ct * 512 + lane * 4;
            f16x8 b1 = ld_frag(bb);
            f16x8 b2 = ld_frag(bb + 256);
            f32x4 c0 = acc[0][ct], c1 = acc[1][ct];
            f32x4 d0 = ac2[0][ct], d1 = ac2[1][ct];
            c0 = __builtin_amdgcn_mfma_f32_16x16x32_f16(a1[0], b1, c0, 0, 0, 0);
            c1 = __builtin_amdgcn_mfma_f32_16x16x32_f16(a1[1], b1, c1, 0, 0, 0);
            d0 = __builtin_amdgcn_mfma_f32_16x16x32_f16(a1[0], b2, d0, 0, 0, 0);
            d1 = __builtin_amdgcn_mfma_f32_16x16x32_f16(a1[1], b2, d1, 0, 0, 0);
            d0 = __builtin_amdgcn_mfma_f32_16x16x32_f16(a2[0], b1, d0, 0, 0, 0);
            d1 = __builtin_amdgcn_mfma_f32_16x16x32_f16(a2[1], b1, d1, 0, 0, 0);
            acc[0][ct] = c0; acc[1][ct] = c1;
            ac2[0][ct] = d0; ac2[1][ct] = d1;
        }
    }

    // fold the scaled-residual accumulator back: proj = acc + ac2 * 2^-12
    #pragma unroll
    for (int rt = 0; rt < 2; ++rt)
        #pragma unroll
        for (int ct = 0; ct < 4; ++ct)
            #pragma unroll
            for (int r = 0; r < 4; ++r)
                acc[rt][ct][r] = fmaf(ac2[rt][ct][r], IRSC, acc[rt][ct][r]);

    // ---- per-token L2 norm from fragments ----
    float inv_n[2][4];
    #pragma unroll
    for (int rt = 0; rt < 2; ++rt) {
        #pragma unroll
        for (int r = 0; r < 4; ++r) {
            float ss = 0.f;
            #pragma unroll
            for (int ct = 0; ct < 4; ++ct)
                ss = fmaf(acc[rt][ct][r], acc[rt][ct][r], ss);
            ss += __shfl_xor(ss, 1, 64);
            ss += __shfl_xor(ss, 2, 64);
            ss += __shfl_xor(ss, 4, 64);
            ss += __shfl_xor(ss, 8, 64);
            inv_n[rt][r] = 1.0f / fmaxf(sqrtf(ss), 1e-12f);
        }
    }

    __syncthreads();   // all waves done with staging LDS (h_norm overlays it)

    // h_norm -> smem as [tok][d], stride 68; each wave touches only its tokens
    #pragma unroll
    for (int rt = 0; rt < 2; ++rt)
        #pragma unroll
        for (int ct = 0; ct < 4; ++ct)
            #pragma unroll
            for (int r = 0; r < 4; ++r) {
                const int t = wv * 32 + rt * 16 + lk * 4 + r;
                smem[t * LD2 + ct * 16 + lr] = acc[rt][ct][r] * inv_n[rt][r];
            }

    // ---- stage 2 (MFMA, f16 2-plane): scores[32][64] per wave ----
    const unsigned int* wsE = wsW + WS_EN;
    f32x4 sc[2][4], sc2[2][4];
    #pragma unroll
    for (int rt = 0; rt < 2; ++rt)
        #pragma unroll
        for (int ce = 0; ce < 4; ++ce) {
            sc[rt][ce]  = (f32x4){0.f, 0.f, 0.f, 0.f};
            sc2[rt][ce] = (f32x4){0.f, 0.f, 0.f, 0.f};
        }

    #pragma unroll
    for (int k2 = 0; k2 < 2; ++k2) {
        f16x8 ha1[2], ha2[2];
        #pragma unroll
        for (int rt = 0; rt < 2; ++rt) {
            const float* ra = smem + (wv * 32 + rt * 16 + lr) * LD2 + k2 * 32 + lk * 8;
            float4 lo = *(const float4*)ra;
            float4 hi = *(const float4*)(ra + 4);
            splitf16(lo, hi, ha1[rt], ha2[rt]);
        }
        #pragma unroll
        for (int ce = 0; ce < 4; ++ce) {
            const unsigned int* bb = wsE + (k2 * 4 + ce) * 512 + lane * 4;
            f16x8 b1 = ld_frag(bb);
            f16x8 b2 = ld_frag(bb + 256);
            #pragma unroll
            for (int rt = 0; rt < 2; ++rt) {
                f32x4 c = sc[rt][ce], d = sc2[rt][ce];
                c = __builtin_amdgcn_mfma_f32_16x16x32_f16(ha1[rt], b1, c, 0, 0, 0);
                d = __builtin_amdgcn_mfma_f32_16x16x32_f16(ha1[rt], b2, d, 0, 0, 0);
                d = __builtin_amdgcn_mfma_f32_16x16x32_f16(ha2[rt], b1, d, 0, 0, 0);
                sc[rt][ce] = c; sc2[rt][ce] = d;
            }
        }
    }

    // ---- epilogue on C-fragment layout; top-2 first, m = v1 ----
    const float inv_tau = 1.0f / tau_p[0];
    float* outS = out;                        // sparse_gates [NT][64]
    float* outI = out + (size_t)NT * 64;      // topk_indices [NT][2] (as float)
    float* outF = out + (size_t)NT * 66;      // full_gates   [NT][64]

    #pragma unroll
    for (int rt = 0; rt < 2; ++rt) {
        #pragma unroll
        for (int r = 0; r < 4; ++r) {
            const long tok = tok0 + wv * 32 + rt * 16 + lk * 4 + r;
            float s[4];
            #pragma unroll
            for (int ce = 0; ce < 4; ++ce)
                s[ce] = fmaf(sc2[rt][ce][r], IRSC, sc[rt][ce][r]) * inv_tau;

            // top-2 via order-preserving u64 keys: (ord(v) << 6) | (63 - e).
            unsigned long long k1 = 0ULL, k2 = 0ULL;   // 0 < any real key
            #pragma unroll
            for (int ce = 0; ce < 4; ++ce) {
                unsigned int ou = __float_as_uint(s[ce]);
                ou = (ou & 0x80000000u) ? ~ou : (ou | 0x80000000u);
                unsigned long long key = ((unsigned long long)ou << 6)
                                       | (unsigned long long)(63 - (ce * 16 + lr));
                if (key > k1) { k2 = k1; k1 = key; }
                else if (key > k2) { k2 = key; }
            }
            #pragma unroll
            for (int msk = 1; msk <= 8; msk <<= 1) {
                unsigned long long o1 = __shfl_xor(k1, msk, 64);
                unsigned long long o2 = __shfl_xor(k2, msk, 64);
                unsigned long long hi = k1 > o1 ? k1 : o1;
                unsigned long long lo = k1 > o1 ? o1 : k1;
                unsigned long long m2 = k2 > o2 ? k2 : o2;
                k2 = lo > m2 ? lo : m2;
                k1 = hi;
            }
            const int i1 = 63 - (int)(k1 & 63ULL);
            const int i2 = 63 - (int)(k2 & 63ULL);
            const unsigned int u1 = (unsigned int)(k1 >> 6);
            const unsigned int u2 = (unsigned int)(k2 >> 6);
            const float v1 = __uint_as_float((u1 & 0x80000000u) ? (u1 ^ 0x80000000u) : ~u1);
            const float v2 = __uint_as_float((u2 & 0x80000000u) ? (u2 ^ 0x80000000u) : ~u2);

            // softmax max == v1 (top-1 score): no separate max-reduction
            const float m = v1;

            float g[4], z = 0.f;
            #pragma unroll
            for (int ce = 0; ce < 4; ++ce) { g[ce] = __expf(s[ce] - m); z += g[ce]; }
            z += __shfl_xor(z, 1, 64);
            z += __shfl_xor(z, 2, 64);
            z += __shfl_xor(z, 4, 64);
            z += __shfl_xor(z, 8, 64);
            const float invZ = 1.0f / z;

            #pragma unroll
            for (int ce = 0; ce < 4; ++ce)
                outF[tok * 64 + ce * 16 + lr] = g[ce] * invZ;

            // softmax over the two top GATE values; gv1 = exp(0)*invZ = invZ
            const float gv1 = invZ;
            const float gv2 = __expf(v2 - m) * invZ;
            const float qq = __expf(gv2 - gv1);
            const float w1 = 1.0f / (1.0f + qq);
            const float w2 = qq * w1;

            #pragma unroll
            for (int ce = 0; ce < 4; ++ce) {
                int e = ce * 16 + lr;
                outS[tok * 64 + e] = (e == i1) ? w1 : ((e == i2) ? w2 : 0.0f);
            }
            if (lr == 0) {
                *(float2*)(outI + tok * 2) = make_float2((float)i1, (float)i2);
            }
        }
    }
#undef STAGE_A
#undef STAGE_B
}

extern "C" void kernel_launch(void* const* d_in, const int* in_sizes, int n_in,
                              void* d_out, int out_size, void* d_ws, size_t ws_size,
                              hipStream_t stream) {
    const float* h   = (const float*)d_in[0];
    const float* W   = (const float*)d_in[1];
    const float* E   = (const float*)d_in[2];
    const float* tau = (const float*)d_in[3];
    float* out = (float*)d_out;
    unsigned int* ws = (unsigned int*)d_ws;   // 128KB W frags + 16KB e_norm frags

    prep<<<17, 256, 0, stream>>>(W, E, ws);
    moe_all<<<NT / BM, 256, 0, stream>>>(h, ws, tau, out);
}